// Round 3
// baseline (109.238 us; speedup 1.0000x reference)
//
#include <hip/hip_runtime.h>

#define NRAD 16
#define NCH  5
#define NMON 35
#define OUTW 144   // 16 + 4*32

// ---------------- Kernel A: segment offsets from sorted index ---------------
__global__ __launch_bounds__(256) void seg_offsets(
    const int* __restrict__ idx, int* __restrict__ seg, int E, int nat)
{
    int e = blockIdx.x * blockDim.x + threadIdx.x;
    if (e >= E) return;
    if (e == 0) {
        const int b = idx[0];
        for (int n = 0; n <= b; ++n) seg[n] = 0;
    } else {
        const int a = idx[e - 1], b = idx[e];
        for (int n = a + 1; n <= b; ++n) seg[n] = e;
    }
    if (e == E - 1) {
        const int a = idx[E - 1];
        for (int n = a + 1; n <= nat; ++n) seg[n] = E;
    }
}

// ---------------- edge inner body ------------------------------------------
__device__ __forceinline__ void edge_body(
    float x, float y, float z, float rad, float c4,
    float acc[NMON], float& acc2)
{
    const float x2 = x * x, x3 = x2 * x, x4 = x2 * x2;
    const float y2 = y * y, y3 = y2 * y, y4 = y2 * y2;
    const float z2 = z * z, z3 = z2 * z, z4 = z2 * z2;
    const float xy = x * y, xz = x * z, yz = y * z;

    acc2 += c4;
    acc[0]  += rad;
    acc[1]  = fmaf(rad, z,        acc[1]);
    acc[2]  = fmaf(rad, y,        acc[2]);
    acc[3]  = fmaf(rad, x,        acc[3]);
    acc[4]  = fmaf(rad, z2,       acc[4]);
    acc[5]  = fmaf(rad, yz,       acc[5]);
    acc[6]  = fmaf(rad, y2,       acc[6]);
    acc[7]  = fmaf(rad, xz,       acc[7]);
    acc[8]  = fmaf(rad, xy,       acc[8]);
    acc[9]  = fmaf(rad, x2,       acc[9]);
    acc[10] = fmaf(rad, z3,       acc[10]);
    acc[11] = fmaf(rad, y * z2,   acc[11]);
    acc[12] = fmaf(rad, y2 * z,   acc[12]);
    acc[13] = fmaf(rad, y3,       acc[13]);
    acc[14] = fmaf(rad, x * z2,   acc[14]);
    acc[15] = fmaf(rad, xy * z,   acc[15]);
    acc[16] = fmaf(rad, x * y2,   acc[16]);
    acc[17] = fmaf(rad, x2 * z,   acc[17]);
    acc[18] = fmaf(rad, x2 * y,   acc[18]);
    acc[19] = fmaf(rad, x3,       acc[19]);
    acc[20] = fmaf(rad, z4,       acc[20]);
    acc[21] = fmaf(rad, y * z3,   acc[21]);
    acc[22] = fmaf(rad, y2 * z2,  acc[22]);
    acc[23] = fmaf(rad, y3 * z,   acc[23]);
    acc[24] = fmaf(rad, y4,       acc[24]);
    acc[25] = fmaf(rad, x * z3,   acc[25]);
    acc[26] = fmaf(rad, xy * z2,  acc[26]);
    acc[27] = fmaf(rad, x * y2 * z, acc[27]);
    acc[28] = fmaf(rad, x * y3,   acc[28]);
    acc[29] = fmaf(rad, x2 * z2,  acc[29]);
    acc[30] = fmaf(rad, x2 * yz,  acc[30]);
    acc[31] = fmaf(rad, x2 * y2,  acc[31]);
    acc[32] = fmaf(rad, x3 * z,   acc[32]);
    acc[33] = fmaf(rad, x3 * y,   acc[33]);
    acc[34] = fmaf(rad, x4,       acc[34]);
}

// ---------------- Kernel B: TWO waves per atom, LDS pairwise reduce --------
// block = 256 threads = 4 waves = 2 atoms. 2000 blocks -> 8000 waves (~6-8/SIMD).
__global__ __launch_bounds__(256) void mbp_main(
    const float* __restrict__ rij_unit,
    const float* __restrict__ radial_ij,
    const float* __restrict__ lambda_w,
    const float* __restrict__ fact_norm,
    const int*   __restrict__ seg,
    float* __restrict__ out,
    int nat)
{
    const int wave  = threadIdx.x >> 6;
    const int atomw = wave >> 1;          // 0..1 within block
    const int half  = wave & 1;           // which half of the edge list
    const int n = blockIdx.x * 2 + atomw;
    const int lane = threadIdx.x & 63;
    const int zi = lane >> 4;
    const int r  = lane & 15;

    float acc[NMON];
    #pragma unroll
    for (int l = 0; l < NMON; ++l) acc[l] = 0.f;
    float acc2 = 0.f;

    int start = 0, end = 0;
    if (n < nat) { start = seg[n]; end = seg[n + 1]; }

    const int roff = r * NCH + zi;
    const int coff = r * NCH + 4;

    int e = start + half;
    // 4 edges per iteration at stride 2: e, e+2, e+4, e+6
    for (; e + 6 < end; e += 8) {
        float xs[4], ys[4], zs[4], rd[4], c4[4];
        #pragma unroll
        for (int u = 0; u < 4; ++u) {
            const int ee = e + 2 * u;
            xs[u] = rij_unit[ee * 3 + 0];
            ys[u] = rij_unit[ee * 3 + 1];
            zs[u] = rij_unit[ee * 3 + 2];
            rd[u] = radial_ij[ee * (NRAD * NCH) + roff];
            c4[u] = radial_ij[ee * (NRAD * NCH) + coff];
        }
        #pragma unroll
        for (int u = 0; u < 4; ++u)
            edge_body(xs[u], ys[u], zs[u], rd[u], c4[u], acc, acc2);
    }
    for (; e < end; e += 2) {
        const float x = rij_unit[e * 3 + 0];
        const float y = rij_unit[e * 3 + 1];
        const float z = rij_unit[e * 3 + 2];
        const float rad = radial_ij[e * (NRAD * NCH) + roff];
        const float c4v = radial_ij[e * (NRAD * NCH) + coff];
        edge_body(x, y, z, rad, c4v, acc, acc2);
    }

    // pairwise cross-wave reduce: half==1 publishes, half==0 combines.
    __shared__ float red[2][NMON + 1][64];   // [l][lane]: 2-way bank alias = free
    if (half == 1) {
        #pragma unroll
        for (int l = 0; l < NMON; ++l) red[atomw][l][lane] = acc[l];
        red[atomw][NMON][lane] = acc2;
    }
    __syncthreads();
    if (half == 1 || n >= nat) return;

    #pragma unroll
    for (int l = 0; l < NMON; ++l) acc[l] += red[atomw][l][lane];
    acc2 += red[atomw][NMON][lane];

    const float l0 = lambda_w[0], l1 = lambda_w[1];
    const float p0[5] = {1.f, l0, l0 * l0, l0 * l0 * l0, (l0 * l0) * (l0 * l0)};
    const float p1[5] = {1.f, l1, l1 * l1, l1 * l1 * l1, (l1 * l1) * (l1 * l1)};
    const int lsum_tab[NMON] = {0, 1,1,1, 2,2,2,2,2,2,
                                3,3,3,3,3,3,3,3,3,3,
                                4,4,4,4,4,4,4,4,4,4,4,4,4,4,4};
    float s0 = 0.f, s1 = 0.f;
    #pragma unroll
    for (int l = 0; l < NMON; ++l) {
        const float v = acc[l] * fact_norm[l];
        const float v2 = v * v;
        s0 = fmaf(v2, p0[lsum_tab[l]], s0);
        s1 = fmaf(v2, p1[lsum_tab[l]], s1);
    }
    const float scale = 1.0f / (float)(1 << zi);   // 2^(1-zeta)
    float* orow = out + (long)n * OUTW;
    orow[16 + zi * 32 + r * 2 + 0] = s0 * scale;
    orow[16 + zi * 32 + r * 2 + 1] = s1 * scale;
    if (zi == 0) orow[r] = acc2;
}

extern "C" void kernel_launch(void* const* d_in, const int* in_sizes, int n_in,
                              void* d_out, int out_size, void* d_ws, size_t ws_size,
                              hipStream_t stream) {
    const float* rij_unit   = (const float*)d_in[0];
    const float* radial_ij  = (const float*)d_in[1];
    const float* lambda_w   = (const float*)d_in[2];
    const float* fact_norm  = (const float*)d_in[3];
    const int*   first_atom = (const int*)d_in[4];
    const int E   = in_sizes[4];
    const int nat = out_size / OUTW;

    int* seg = (int*)d_ws;   // nat+1 ints

    seg_offsets<<<(E + 255) / 256, 256, 0, stream>>>(first_atom, seg, E, nat);
    mbp_main<<<(nat + 1) / 2, 256, 0, stream>>>(rij_unit, radial_ij, lambda_w,
                                                fact_norm, seg, (float*)d_out, nat);
}

// Round 4
// 106.317 us; speedup vs baseline: 1.0275x; 1.0275x over previous
//
#include <hip/hip_runtime.h>

#define NRAD 16
#define NCH  5
#define NMON 35
#define OUTW 144   // 16 + 4*32
#define TILE 64
#define ROWF (NRAD * NCH)   // 80 floats per edge row

// ---------------- Kernel A: segment offsets from sorted index ---------------
__global__ __launch_bounds__(256) void seg_offsets(
    const int* __restrict__ idx, int* __restrict__ seg, int E, int nat)
{
    int e = blockIdx.x * blockDim.x + threadIdx.x;
    if (e >= E) return;
    if (e == 0) {
        const int b = idx[0];
        for (int n = 0; n <= b; ++n) seg[n] = 0;
    } else {
        const int a = idx[e - 1], b = idx[e];
        for (int n = a + 1; n <= b; ++n) seg[n] = e;
    }
    if (e == E - 1) {
        const int a = idx[E - 1];
        for (int n = a + 1; n <= nat; ++n) seg[n] = E;
    }
}

// ---------------- edge inner body ------------------------------------------
__device__ __forceinline__ void edge_body(
    float x, float y, float z, float rad, float c4,
    float acc[NMON], float& acc2)
{
    const float x2 = x * x, x3 = x2 * x, x4 = x2 * x2;
    const float y2 = y * y, y3 = y2 * y, y4 = y2 * y2;
    const float z2 = z * z, z3 = z2 * z, z4 = z2 * z2;
    const float xy = x * y, xz = x * z, yz = y * z;

    acc2 += c4;
    acc[0]  += rad;
    acc[1]  = fmaf(rad, z,        acc[1]);
    acc[2]  = fmaf(rad, y,        acc[2]);
    acc[3]  = fmaf(rad, x,        acc[3]);
    acc[4]  = fmaf(rad, z2,       acc[4]);
    acc[5]  = fmaf(rad, yz,       acc[5]);
    acc[6]  = fmaf(rad, y2,       acc[6]);
    acc[7]  = fmaf(rad, xz,       acc[7]);
    acc[8]  = fmaf(rad, xy,       acc[8]);
    acc[9]  = fmaf(rad, x2,       acc[9]);
    acc[10] = fmaf(rad, z3,       acc[10]);
    acc[11] = fmaf(rad, y * z2,   acc[11]);
    acc[12] = fmaf(rad, y2 * z,   acc[12]);
    acc[13] = fmaf(rad, y3,       acc[13]);
    acc[14] = fmaf(rad, x * z2,   acc[14]);
    acc[15] = fmaf(rad, xy * z,   acc[15]);
    acc[16] = fmaf(rad, x * y2,   acc[16]);
    acc[17] = fmaf(rad, x2 * z,   acc[17]);
    acc[18] = fmaf(rad, x2 * y,   acc[18]);
    acc[19] = fmaf(rad, x3,       acc[19]);
    acc[20] = fmaf(rad, z4,       acc[20]);
    acc[21] = fmaf(rad, y * z3,   acc[21]);
    acc[22] = fmaf(rad, y2 * z2,  acc[22]);
    acc[23] = fmaf(rad, y3 * z,   acc[23]);
    acc[24] = fmaf(rad, y4,       acc[24]);
    acc[25] = fmaf(rad, x * z3,   acc[25]);
    acc[26] = fmaf(rad, xy * z2,  acc[26]);
    acc[27] = fmaf(rad, x * y2 * z, acc[27]);
    acc[28] = fmaf(rad, x * y3,   acc[28]);
    acc[29] = fmaf(rad, x2 * z2,  acc[29]);
    acc[30] = fmaf(rad, x2 * yz,  acc[30]);
    acc[31] = fmaf(rad, x2 * y2,  acc[31]);
    acc[32] = fmaf(rad, x3 * z,   acc[32]);
    acc[33] = fmaf(rad, x3 * y,   acc[33]);
    acc[34] = fmaf(rad, x4,       acc[34]);
}

// ---------------- Kernel B: one atom per block, LDS-staged tiles -----------
// Global loads are exact-size, perfectly coalesced float4; compute reads LDS.
__global__ __launch_bounds__(256) void mbp_main(
    const float* __restrict__ rij_unit,
    const float* __restrict__ radial_ij,
    const float* __restrict__ lambda_w,
    const float* __restrict__ fact_norm,
    const int*   __restrict__ seg,
    float* __restrict__ out,
    int nat)
{
    __shared__ float rad_t[TILE * ROWF];   // 20 KB; reused for reduction
    __shared__ float rij_t[TILE * 3];

    const int n    = blockIdx.x;
    const int tid  = threadIdx.x;
    const int wave = tid >> 6;
    const int lane = tid & 63;
    const int zi   = lane >> 4;
    const int r    = lane & 15;

    const int start = seg[n];
    const int end   = seg[n + 1];

    float acc[NMON];
    #pragma unroll
    for (int l = 0; l < NMON; ++l) acc[l] = 0.f;
    float acc2 = 0.f;

    for (int ts = start; ts < end; ts += TILE) {
        const int T = min(TILE, end - ts);

        // stage radial: T*80 floats = T*20 float4, contiguous & coalesced
        {
            const float4* __restrict__ src = (const float4*)(radial_ij + (size_t)ts * ROWF);
            float4* dst = (float4*)rad_t;
            const int nf4 = T * (ROWF / 4);
            for (int i = tid; i < nf4; i += 256) dst[i] = src[i];
        }
        // stage rij: T*3 floats
        for (int i = tid; i < T * 3; i += 256) rij_t[i] = rij_unit[(size_t)ts * 3 + i];
        __syncthreads();

        // compute: wave w handles edges w, w+4, ... within [0, T)
        for (int j = wave; j < T; j += 4) {
            const float x   = rij_t[j * 3 + 0];
            const float y   = rij_t[j * 3 + 1];
            const float z   = rij_t[j * 3 + 2];
            const float rad = rad_t[j * ROWF + r * NCH + zi];
            const float c4  = rad_t[j * ROWF + r * NCH + 4];
            edge_body(x, y, z, rad, c4, acc, acc2);
        }
        __syncthreads();
    }

    // cross-wave reduction, reusing rad_t: red[region][NMON+1][64]
    float* red = rad_t;
    const int region = wave >> 1;                    // pair (0,1)->0, (2,3)->1
    const int rbase  = region * (NMON + 1) * 64;

    if (wave & 1) {                                  // waves 1,3 publish
        #pragma unroll
        for (int l = 0; l < NMON; ++l) red[rbase + l * 64 + lane] = acc[l];
        red[rbase + NMON * 64 + lane] = acc2;
    }
    __syncthreads();
    if (!(wave & 1)) {                               // waves 0,2 combine
        #pragma unroll
        for (int l = 0; l < NMON; ++l) acc[l] += red[rbase + l * 64 + lane];
        acc2 += red[rbase + NMON * 64 + lane];
    }
    __syncthreads();
    if (wave == 2) {                                 // wave 2 republishes into region 1
        #pragma unroll
        for (int l = 0; l < NMON; ++l) red[rbase + l * 64 + lane] = acc[l];
        red[rbase + NMON * 64 + lane] = acc2;
    }
    __syncthreads();
    if (wave != 0) return;

    const int r1base = (NMON + 1) * 64;
    #pragma unroll
    for (int l = 0; l < NMON; ++l) acc[l] += red[r1base + l * 64 + lane];
    acc2 += red[r1base + NMON * 64 + lane];

    // epilogue
    const float l0 = lambda_w[0], l1 = lambda_w[1];
    const float p0[5] = {1.f, l0, l0 * l0, l0 * l0 * l0, (l0 * l0) * (l0 * l0)};
    const float p1[5] = {1.f, l1, l1 * l1, l1 * l1 * l1, (l1 * l1) * (l1 * l1)};
    const int lsum_tab[NMON] = {0, 1,1,1, 2,2,2,2,2,2,
                                3,3,3,3,3,3,3,3,3,3,
                                4,4,4,4,4,4,4,4,4,4,4,4,4,4,4};
    float s0 = 0.f, s1 = 0.f;
    #pragma unroll
    for (int l = 0; l < NMON; ++l) {
        const float v = acc[l] * fact_norm[l];
        const float v2 = v * v;
        s0 = fmaf(v2, p0[lsum_tab[l]], s0);
        s1 = fmaf(v2, p1[lsum_tab[l]], s1);
    }
    const float scale = 1.0f / (float)(1 << zi);   // 2^(1-zeta)
    float* orow = out + (long)n * OUTW;
    orow[16 + zi * 32 + r * 2 + 0] = s0 * scale;
    orow[16 + zi * 32 + r * 2 + 1] = s1 * scale;
    if (zi == 0) orow[r] = acc2;
}

extern "C" void kernel_launch(void* const* d_in, const int* in_sizes, int n_in,
                              void* d_out, int out_size, void* d_ws, size_t ws_size,
                              hipStream_t stream) {
    const float* rij_unit   = (const float*)d_in[0];
    const float* radial_ij  = (const float*)d_in[1];
    const float* lambda_w   = (const float*)d_in[2];
    const float* fact_norm  = (const float*)d_in[3];
    const int*   first_atom = (const int*)d_in[4];
    const int E   = in_sizes[4];
    const int nat = out_size / OUTW;

    int* seg = (int*)d_ws;   // nat+1 ints

    seg_offsets<<<(E + 255) / 256, 256, 0, stream>>>(first_atom, seg, E, nat);
    mbp_main<<<nat, 256, 0, stream>>>(rij_unit, radial_ij, lambda_w,
                                      fact_norm, seg, (float*)d_out, nat);
}